// Round 1
// baseline (410.547 us; speedup 1.0000x reference)
//
#include <hip/hip_runtime.h>

// B=16, L=2048, V=64.
// Algebraic reduction (e is one-hot):
//   E[d] = exp(v_emb[d]); S[t] = prefix_sum(E)[t]
//   F[b,c,s] = sum_{s'<=s} E[s-s'] * Wq[idx[b,s'], c]        (causal Toeplitz GEMM)
//   P[b,c,s] = exp(F[b,c,s] / S[s])                          (softmax w/o max; scores ~ +-0.01)
//   l2[b,t,v] = Wv00 * (sum_{s<=t, idx[b,s]==v} P[b,c_t,s]) / (sum_{s<=t} P[b,c_t,s])
//   with c_t = idx[b,t].

#define LSEQ 2048
#define NB 16
#define NV 64

// ---------------- K0: E = exp(v_emb), S = inclusive prefix sum of E -------------
__global__ __launch_bounds__(64) void k_prep(const float* __restrict__ v_emb,
                                             float* __restrict__ E,
                                             float* __restrict__ S) {
  const int lane = threadIdx.x;          // 0..63, each lane owns 32 contiguous elems
  const int base = lane * 32;
  float e[32];
  float run = 0.f;
#pragma unroll
  for (int i = 0; i < 32; ++i) { e[i] = expf(v_emb[base + i]); run += e[i]; }
  // wave-inclusive scan of per-lane chunk sums
  float incl = run;
#pragma unroll
  for (int d = 1; d < 64; d <<= 1) {
    float up = __shfl_up(incl, d);
    if (lane >= d) incl += up;
  }
  float acc = incl - run;  // exclusive prefix of this lane's chunk
#pragma unroll
  for (int i = 0; i < 32; ++i) {
    acc += e[i];
    E[base + i] = e[i];
    S[base + i] = acc;
  }
}

// ---------------- K1: P[(b*64+c)][s] = exp(F[b,c,s]/S[s]) ----------------------
// GEMM C'[m=(b,c)][n=s] = sum_k A[m][k] * Bt[k][n]
//   A[m=(b,c)][k=s'] = Wq[idx[b,s'], c]      (generated on the fly, row-gather)
//   Bt[k=s'][n=s]    = (s' <= s) ? E[s-s'] : 0   (generated on the fly from E)
// Block: BM=64 (one b, all 64 c), BN=64 (s chunk), BK=64. 256 threads, 4x4/thread.
__global__ __launch_bounds__(256) void k_gemm(const int* __restrict__ idx,
                                              const float* __restrict__ Wq,
                                              const float* __restrict__ E,
                                              const float* __restrict__ S,
                                              float* __restrict__ P) {
  __shared__ float As[64][64];   // [k][c]
  __shared__ float Bs[64][64];   // [k][n]
  __shared__ float eb[128];      // E window for this (n0,k0) diagonal band
  __shared__ int ii[64];         // idx[b, k0..k0+63]

  const int b  = blockIdx.y;                 // 0..15
  const int bn = 31 - (int)blockIdx.x;       // heavy (long-K) blocks launch first
  const int n0 = bn * 64;
  const int tid = threadIdx.x;
  const int tm = tid & 15;                   // m quad: c = tm*4 + i
  const int tn = tid >> 4;                   // n quad: s = n0 + tn*4 + j

  float acc[4][4];
#pragma unroll
  for (int i = 0; i < 4; ++i)
#pragma unroll
    for (int j = 0; j < 4; ++j) acc[i][j] = 0.f;

  const int kiters = bn + 1;                 // causal: k0 <= n0
  for (int it = 0; it < kiters; ++it) {
    const int k0 = it * 64;
    const int dbase = n0 - k0;               // >= 0
    __syncthreads();                         // protect LDS reuse across iters
    if (tid < 64) ii[tid] = idx[b * LSEQ + k0 + tid];
    if (tid < 127) {                         // d in [dbase-63, dbase+63]
      const int d = dbase - 63 + tid;
      eb[tid] = (d >= 0) ? E[d] : 0.f;       // d<=2047 guaranteed (n0-k0+63<=2047)
    }
    __syncthreads();
    // fill As and Bs: each thread 4 float4s of each
    {
      const int f4 = tid & 15;               // column quad (16B)
      const int kb = tid >> 4;               // 0..15
#pragma unroll
      for (int r = 0; r < 4; ++r) {
        const int k = kb + r * 16;
        const float4 w = *(const float4*)(Wq + ii[k] * 64 + f4 * 4);
        *(float4*)(&As[k][f4 * 4]) = w;
        const int e0 = f4 * 4 - k + 63;      // in [0,126]
        float4 bv;
        bv.x = eb[e0 + 0];
        bv.y = eb[e0 + 1];
        bv.z = eb[e0 + 2];
        bv.w = eb[e0 + 3];
        *(float4*)(&Bs[k][f4 * 4]) = bv;
      }
    }
    __syncthreads();
#pragma unroll 8
    for (int kk = 0; kk < 64; ++kk) {
      const float4 a  = *(const float4*)(&As[kk][tm * 4]);
      const float4 bb = *(const float4*)(&Bs[kk][tn * 4]);
      const float av[4] = {a.x, a.y, a.z, a.w};
      const float bv[4] = {bb.x, bb.y, bb.z, bb.w};
#pragma unroll
      for (int i = 0; i < 4; ++i)
#pragma unroll
        for (int j = 0; j < 4; ++j)
          acc[i][j] = fmaf(av[i], bv[j], acc[i][j]);
    }
  }
  // epilogue: P[(b*64+c)*2048 + s] = exp(acc / S[s])
  float sinv[4];
#pragma unroll
  for (int j = 0; j < 4; ++j) sinv[j] = 1.0f / S[n0 + tn * 4 + j];
#pragma unroll
  for (int i = 0; i < 4; ++i) {
    float4 st;
    st.x = expf(acc[i][0] * sinv[0]);
    st.y = expf(acc[i][1] * sinv[1]);
    st.z = expf(acc[i][2] * sinv[2]);
    st.w = expf(acc[i][3] * sinv[3]);
    const int m = b * 64 + tm * 4 + i;
    *(float4*)(P + (size_t)m * LSEQ + n0 + tn * 4) = st;
  }
}

// ---------------- K2: per-(b,c) running-histogram scan, emit at idx[b,t]==c ----
// lane v holds bin v. All loads are wave-uniform (scalarizable).
__global__ __launch_bounds__(64) void k_scan(const int* __restrict__ idx,
                                             const float* __restrict__ P,
                                             const float* __restrict__ Wv,
                                             float* __restrict__ out) {
  const int bc = blockIdx.x;       // b*64 + c
  const int b = bc >> 6;
  const int c = bc & 63;
  const int lane = threadIdx.x;
  const float wv = Wv[0];
  const float* __restrict__ prow = P + (size_t)bc * LSEQ;
  const int* __restrict__ irow = idx + b * LSEQ;
  float* __restrict__ obase = out + (size_t)b * LSEQ * 64;
  float bin = 0.f, z = 0.f;
#pragma unroll 16
  for (int s = 0; s < LSEQ; ++s) {
    const float p = prow[s];       // uniform
    const int ic = irow[s];        // uniform
    z += p;
    bin += (lane == ic) ? p : 0.f;
    if (ic == c) {                 // wave-uniform branch; each (b,t) emitted once
      obase[(size_t)s * 64 + lane] = wv * bin / z;   // coalesced 256B store
    }
  }
}

extern "C" void kernel_launch(void* const* d_in, const int* in_sizes, int n_in,
                              void* d_out, int out_size, void* d_ws, size_t ws_size,
                              hipStream_t stream) {
  const int* idx     = (const int*)d_in[0];     // [16, 2048]
  const float* Wq    = (const float*)d_in[1];   // [64, 64]
  const float* Wv    = (const float*)d_in[2];   // [64, 64] (only [0,0] used)
  const float* v_emb = (const float*)d_in[3];   // [2048, 1]
  float* out = (float*)d_out;                   // [16, 2048, 64] fp32

  // workspace layout (fp32): E[2048] | S[2048] | P[1024*2048]  (~8.02 MB)
  float* E = (float*)d_ws;
  float* S = E + LSEQ;
  float* P = S + LSEQ;

  k_prep<<<1, 64, 0, stream>>>(v_emb, E, S);
  k_gemm<<<dim3(32, 16), 256, 0, stream>>>(idx, Wq, E, S, P);
  k_scan<<<NB * NV, 64, 0, stream>>>(idx, P, Wv, out);
}

// Round 3
// 350.696 us; speedup vs baseline: 1.1707x; 1.1707x over previous
//
#include <hip/hip_runtime.h>

// B=16, L=2048, V=64.
// Algebraic reduction (e is one-hot):
//   E[d] = exp(v_emb[d]); S[t] = prefix_sum(E)[t]
//   F[b,c,s] = sum_{s'<=s} E[s-s'] * Wq[idx[b,s'], c]        (causal Toeplitz GEMM)
//   P[b,c,s] = exp(F[b,c,s] / S[s])                          (softmax w/o max; scores ~ +-0.01)
//   out[b,t,v] = Wv00 * (sum_{s<=t, idx[b,s]==v} P[b,c_t,s]) / (sum_{s<=t} P[b,c_t,s])
//   with c_t = idx[b,t].

#define LSEQ 2048
#define NB 16
#define NV 64
#define CS 128            // scan chunk size
#define NC (LSEQ / CS)    // 16 chunks

// ---------------- K0: E = exp(v_emb), S = inclusive prefix sum of E -------------
__global__ __launch_bounds__(64) void k_prep(const float* __restrict__ v_emb,
                                             float* __restrict__ E,
                                             float* __restrict__ S) {
  const int lane = threadIdx.x;          // 0..63, each lane owns 32 contiguous elems
  const int base = lane * 32;
  float e[32];
  float run = 0.f;
#pragma unroll
  for (int i = 0; i < 32; ++i) { e[i] = expf(v_emb[base + i]); run += e[i]; }
  float incl = run;
#pragma unroll
  for (int d = 1; d < 64; d <<= 1) {
    float up = __shfl_up(incl, d);
    if (lane >= d) incl += up;
  }
  float acc = incl - run;  // exclusive prefix of this lane's chunk
#pragma unroll
  for (int i = 0; i < 32; ++i) {
    acc += e[i];
    E[base + i] = e[i];
    S[base + i] = acc;
  }
}

// ---------------- K1: P[(b*64+c)][s] = exp(F[b,c,s]/S[s]) ----------------------
// C'[m=(b,c)][n=s] = sum_k A[m][k]*Bt[k][n],  A[m][k]=Wq[idx[b,k]][c],
// Bt[k][n]=E_pad[n-k] (Toeplitz).  Whole Wq (16KB) + zero-padded E (8.25KB)
// staged in LDS ONCE; one barrier total.  B-operand = 4-reg sliding window
// (1 new ds_read_b32 per k); A-operand = direct b128 broadcast from Wq LDS,
// row selected by __shfl of a register-held idx tile (no per-tile barriers).
__global__ __launch_bounds__(256) void k_gemm(const int* __restrict__ idx,
                                              const float* __restrict__ Wq,
                                              const float* __restrict__ E,
                                              const float* __restrict__ S,
                                              float* __restrict__ P) {
  __shared__ float Wl[64 * 64];     // [row][c]
  __shared__ float Ep[64 + LSEQ];   // 64 leading zeros, then E[0..2047]

  const int b  = blockIdx.y;                 // 0..15
  const int bn = 31 - (int)blockIdx.x;       // heavy (long-K) blocks launch first
  const int n0 = bn * 64;
  const int tid = threadIdx.x;
  const int lane = tid & 63;
  const int tm = tid & 15;                   // c quad: c = tm*4 + i
  const int tn = tid >> 4;                   // n quad: s = n0 + tn*4 + j

  // stage Wq (ALL 4096 floats: 4 rounds x 256 threads x float4) and E_pad
#pragma unroll
  for (int r = 0; r < 4; ++r)
    *(float4*)(Wl + (r * 256 + tid) * 4) = *(const float4*)(Wq + (r * 256 + tid) * 4);
  if (tid < 64) Ep[tid] = 0.f;
  *(float4*)(Ep + 64 + tid * 8)     = *(const float4*)(E + tid * 8);
  *(float4*)(Ep + 64 + tid * 8 + 4) = *(const float4*)(E + tid * 8 + 4);
  __syncthreads();

  float acc[4][4];
#pragma unroll
  for (int i = 0; i < 4; ++i)
#pragma unroll
    for (int j = 0; j < 4; ++j) acc[i][j] = 0.f;

  const int nb = n0 + tn * 4;
  float val[4];                              // sliding window: val[j] = Ep[64 + nb + j - k]
#pragma unroll
  for (int j = 0; j < 4; ++j) val[j] = Ep[64 + nb + j];

  const int kt = bn + 1;                     // causal: k tiles 0..bn
  for (int it = 0; it < kt; ++it) {
    const int k0 = it * 64;
    const int ii = idx[b * LSEQ + k0 + lane];   // wave-uniform source for readlane
#pragma unroll
    for (int kk = 0; kk < 64; ++kk) {
      const int row = __shfl(ii, kk);                       // v_readlane
      const float4 a4 = *(const float4*)(Wl + row * 64 + tm * 4);
      const float nv = Ep[64 + nb - 1 - (k0 + kk)];         // next window element
      const float av[4] = {a4.x, a4.y, a4.z, a4.w};
#pragma unroll
      for (int i = 0; i < 4; ++i)
#pragma unroll
        for (int j = 0; j < 4; ++j)
          acc[i][j] = fmaf(av[i], val[j], acc[i][j]);
      val[3] = val[2]; val[2] = val[1]; val[1] = val[0]; val[0] = nv;
    }
  }

  // epilogue: P[(b*64+c)*2048 + s] = exp(acc / S[s])
  float sinv[4];
#pragma unroll
  for (int j = 0; j < 4; ++j) sinv[j] = 1.0f / S[nb + j];
#pragma unroll
  for (int i = 0; i < 4; ++i) {
    float4 st;
    st.x = expf(acc[i][0] * sinv[0]);
    st.y = expf(acc[i][1] * sinv[1]);
    st.z = expf(acc[i][2] * sinv[2]);
    st.w = expf(acc[i][3] * sinv[3]);
    const int m = b * 64 + tm * 4 + i;
    *(float4*)(P + (size_t)m * LSEQ + nb) = st;
  }
}

// ---------------- K2a: per-(b,c,chunk) local 64-bin histogram ------------------
__global__ __launch_bounds__(64) void k_hist(const int* __restrict__ idx,
                                             const float* __restrict__ P,
                                             float* __restrict__ hist) {
  const int ch = blockIdx.x;    // 0..NC-1
  const int c  = blockIdx.y;    // 0..63
  const int b  = blockIdx.z;    // 0..15
  const int lane = threadIdx.x;
  const int bc = b * 64 + c;
  const float* __restrict__ prow = P + (size_t)bc * LSEQ + ch * CS;
  const int* __restrict__ irow = idx + b * LSEQ + ch * CS;
  float bin = 0.f;
#pragma unroll 8
  for (int s = 0; s < CS; ++s) {
    bin += (lane == irow[s]) ? prow[s] : 0.f;   // uniform loads, per-lane select
  }
  hist[((size_t)bc * NC + ch) * 64 + lane] = bin;
}

// ---------------- K2b: in-place exclusive scan across chunks -------------------
__global__ __launch_bounds__(64) void k_chunkscan(float* __restrict__ hist) {
  const int bc = blockIdx.x;    // 0..1023
  const int lane = threadIdx.x;
  float* h = hist + (size_t)bc * NC * 64 + lane;
  float run = 0.f;
#pragma unroll
  for (int i = 0; i < NC; ++i) {
    const float v = h[i * 64];
    h[i * 64] = run;
    run += v;
  }
}

// ---------------- K2c: per-(b,t) emission ------------------------------------
__global__ __launch_bounds__(64) void k_emit(const int* __restrict__ idx,
                                             const float* __restrict__ P,
                                             const float* __restrict__ hist,
                                             const float* __restrict__ Wv,
                                             float* __restrict__ out) {
  const int t = blockIdx.x;     // 0..2047
  const int b = blockIdx.y;     // 0..15
  const int lane = threadIdx.x;
  const int c = idx[b * LSEQ + t];            // uniform
  const int bc = b * 64 + c;
  const int ch = t / CS;
  float bin = hist[((size_t)bc * NC + ch) * 64 + lane];   // chunk-boundary prefix
  const float* __restrict__ prow = P + (size_t)bc * LSEQ;
  const int* __restrict__ irow = idx + b * LSEQ;
#pragma unroll 4
  for (int s = ch * CS; s <= t; ++s) {
    bin += (lane == irow[s]) ? prow[s] : 0.f;
  }
  float z = bin;
#pragma unroll
  for (int d = 1; d < 64; d <<= 1) z += __shfl_xor(z, d);
  out[((size_t)(b * LSEQ + t)) * 64 + lane] = Wv[0] * bin / z;
}

extern "C" void kernel_launch(void* const* d_in, const int* in_sizes, int n_in,
                              void* d_out, int out_size, void* d_ws, size_t ws_size,
                              hipStream_t stream) {
  const int* idx     = (const int*)d_in[0];     // [16, 2048]
  const float* Wq    = (const float*)d_in[1];   // [64, 64]
  const float* Wv    = (const float*)d_in[2];   // [64, 64] (only [0,0] used)
  const float* v_emb = (const float*)d_in[3];   // [2048, 1]
  float* out = (float*)d_out;                   // [16, 2048, 64] fp32

  // workspace (fp32): E[2048] | S[2048] | P[1024*2048] | hist[1024*NC*64]  ~12.6 MB
  float* E = (float*)d_ws;
  float* S = E + LSEQ;
  float* P = S + LSEQ;
  float* hist = P + (size_t)NB * NV * LSEQ;

  k_prep<<<1, 64, 0, stream>>>(v_emb, E, S);
  k_gemm<<<dim3(32, 16), 256, 0, stream>>>(idx, Wq, E, S, P);
  k_hist<<<dim3(NC, NV, NB), 64, 0, stream>>>(idx, P, hist);
  k_chunkscan<<<NB * NV, 64, 0, stream>>>(hist);
  k_emit<<<dim3(LSEQ, NB), 64, 0, stream>>>(idx, P, hist, Wv, out);
}

// Round 4
// 270.597 us; speedup vs baseline: 1.5172x; 1.2960x over previous
//
#include <hip/hip_runtime.h>

// B=16, L=2048, V=64.
// Algebraic reduction (e is one-hot):
//   E[d] = exp(v_emb[d]); S[t] = prefix_sum(E)[t]
//   F[b,c,s] = sum_{k<=s} E[s-k] * Wq[idx[b,k], c]            (causal Toeplitz GEMM)
//   P[b,c,s] = exp(F[b,c,s] / S[s])                           (softmax w/o max; scores tiny)
//   out[b,t,v] = Wv00 * (sum_{s<=t, idx[b,s]==v} P[b,c_t,s]) / (sum_{s<=t} P[b,c_t,s]),  c_t = idx[b,t]
//
// GEMM is done with bf16 MFMA (16x16x32). K is REVERSED (k'' = 2047-k) so the
// Toeplitz operand E[n-k] = GL[n + k'' - 1920] is k''-contiguous per lane,
// matching the B-fragment layout. Per-lane odd/even start alignment handled by
// two shifted LDS copies (GL0[i]=GLv(i), GL1[i]=GLv(i+1)) + ds_read_b32 x4.
// A operand Agr[b][c][k''] = Wq[idx[b,2047-k'']][c] is pre-gathered to global
// bf16 by k_gather, so the MFMA K-loop has NO barriers and NO scalar gathers.

#define LSEQ 2048
#define NB 16
#define NV 64
#define CS 128            // scan chunk size
#define NC (LSEQ / CS)    // 16 chunks

typedef __attribute__((ext_vector_type(8))) short bf16x8;
typedef __attribute__((ext_vector_type(4))) float f32x4;

__device__ __forceinline__ unsigned short f2bf(float f) {   // RNE float->bf16
  unsigned int u = __float_as_uint(f);
  return (unsigned short)((u + 0x7FFFu + ((u >> 16) & 1u)) >> 16);
}

// ---------------- K0: Ebf = bf16(exp(v_emb)), S = inclusive prefix sum (fp32) --
__global__ __launch_bounds__(64) void k_prep(const float* __restrict__ v_emb,
                                             unsigned short* __restrict__ Ebf,
                                             float* __restrict__ S) {
  const int lane = threadIdx.x;          // each lane owns 32 contiguous elems
  const int base = lane * 32;
  float e[32];
  float run = 0.f;
#pragma unroll
  for (int i = 0; i < 32; ++i) { e[i] = expf(v_emb[base + i]); run += e[i]; }
  float incl = run;
#pragma unroll
  for (int d = 1; d < 64; d <<= 1) {
    float up = __shfl_up(incl, d);
    if (lane >= d) incl += up;
  }
  float acc = incl - run;  // exclusive prefix of this lane's chunk
#pragma unroll
  for (int i = 0; i < 32; ++i) {
    acc += e[i];
    Ebf[base + i] = f2bf(e[i]);
    S[base + i] = acc;
  }
}

// ---------------- K0b: Agr[b][c][k''] = bf16(Wq[idx[b,2047-k'']][c]) -----------
// grid 16b x 8 ktiles(256 k'' each); wave handles 64 k''; lanes = c (coalesced
// Wq row reads); 8 bf16 packed -> one dwordx4 store per 8 k''.
__global__ __launch_bounds__(256) void k_gather(const int* __restrict__ idx,
                                                const float* __restrict__ Wq,
                                                unsigned short* __restrict__ Agr) {
  const int b = blockIdx.x >> 3;
  const int tile = blockIdx.x & 7;
  const int w = threadIdx.x >> 6;
  const int lane = threadIdx.x & 63;
  const int kbase = tile * 256 + w * 64;
#pragma unroll
  for (int r = 0; r < 8; ++r) {
    const int k8 = kbase + r * 8;
    unsigned short v[8];
#pragma unroll
    for (int j = 0; j < 8; ++j) {
      const int ii = idx[b * LSEQ + (2047 - (k8 + j))];   // wave-uniform
      v[j] = f2bf(Wq[ii * 64 + lane]);                    // coalesced row read
    }
    uint4 st;
    st.x = (unsigned int)v[0] | ((unsigned int)v[1] << 16);
    st.y = (unsigned int)v[2] | ((unsigned int)v[3] << 16);
    st.z = (unsigned int)v[4] | ((unsigned int)v[5] << 16);
    st.w = (unsigned int)v[6] | ((unsigned int)v[7] << 16);
    *(uint4*)(Agr + ((size_t)(b * 64 + lane)) * LSEQ + k8) = st;
  }
}

// ---------------- K1: MFMA GEMM -> P[(b*64+c)][s] = exp(F/S[s]) ----------------
// Block = (b, 128-wide n-tile), 4 waves; wave: M=64 (4 m-tiles) x N=32 (2 n-tiles).
// GLv(i) = (127<=i<2175) ? E[i-127] : 0; B[k''][n] = GLv(n + k'' - 1920).
__global__ __launch_bounds__(256) void k_gemm(const unsigned short* __restrict__ Agr,
                                              const unsigned short* __restrict__ Ebf,
                                              const float* __restrict__ S,
                                              float* __restrict__ P) {
  __shared__ unsigned short GL0[2208];   // GL0[i] = GLv(i)   (2208: bank-shifts GL1)
  __shared__ unsigned short GL1[2176];   // GL1[i] = GLv(i+1)

  const int b  = blockIdx.y;
  const int bn = 15 - (int)blockIdx.x;       // heavy (long-K) blocks first
  const int n0 = bn * 128;
  const int tid = threadIdx.x;
  const int w = tid >> 6;
  const int lane = tid & 63;
  const int quad = lane >> 4;
  const int lm = lane & 15;

  for (int i = tid; i < 2208; i += 256) {
    const int e = i - 127;
    GL0[i] = (e >= 0 && e < LSEQ) ? Ebf[e] : (unsigned short)0;
  }
  for (int i = tid; i < 2176; i += 256) {
    const int e = i + 1 - 127;
    GL1[i] = (e >= 0 && e < LSEQ) ? Ebf[e] : (unsigned short)0;
  }
  __syncthreads();

  f32x4 acc[4][2];
#pragma unroll
  for (int mt = 0; mt < 4; ++mt)
#pragma unroll
    for (int nt = 0; nt < 2; ++nt) acc[mt][nt] = (f32x4){0.f, 0.f, 0.f, 0.f};

  const int nbase = n0 + w * 32;             // wave's n base
  const unsigned short* ap[4];
#pragma unroll
  for (int mt = 0; mt < 4; ++mt)
    ap[mt] = Agr + ((size_t)(b * 64 + mt * 16 + lm)) * LSEQ;   // + (k + quad*8)
  int s0[2];
#pragma unroll
  for (int nt = 0; nt < 2; ++nt) s0[nt] = nbase + nt * 16 + lm - 1920;

  const int kstart = 2048 - (n0 + 128);      // causal K extent (k'' reversed)
#pragma unroll 2
  for (int k = kstart; k < 2048; k += 32) {
    const int kq = k + quad * 8;
    union { uint4 u; bf16x8 v; } a[4];
#pragma unroll
    for (int mt = 0; mt < 4; ++mt) a[mt].u = *(const uint4*)(ap[mt] + kq);
    union { unsigned int u[4]; bf16x8 v; } bb[2];
#pragma unroll
    for (int nt = 0; nt < 2; ++nt) {
      const int s = s0[nt] + kq;                       // frag start elem (>=0)
      const unsigned int* base = (s & 1) ? (const unsigned int*)GL1
                                         : (const unsigned int*)GL0;
      const int off = s >> 1;                          // aligned dword index
      bb[nt].u[0] = base[off + 0];
      bb[nt].u[1] = base[off + 1];
      bb[nt].u[2] = base[off + 2];
      bb[nt].u[3] = base[off + 3];
    }
#pragma unroll
    for (int mt = 0; mt < 4; ++mt)
#pragma unroll
      for (int nt = 0; nt < 2; ++nt)
        acc[mt][nt] = __builtin_amdgcn_mfma_f32_16x16x32_bf16(a[mt].v, bb[nt].v,
                                                              acc[mt][nt], 0, 0, 0);
  }

  // epilogue: C/D layout col(s)=lane&15, row(c)=quad*4+reg
  float sinv[2];
#pragma unroll
  for (int nt = 0; nt < 2; ++nt) sinv[nt] = 1.0f / S[nbase + nt * 16 + lm];
#pragma unroll
  for (int mt = 0; mt < 4; ++mt)
#pragma unroll
    for (int nt = 0; nt < 2; ++nt) {
      const int sidx = nbase + nt * 16 + lm;
#pragma unroll
      for (int r = 0; r < 4; ++r) {
        const int c = mt * 16 + quad * 4 + r;
        P[((size_t)(b * 64 + c)) * LSEQ + sidx] = __expf(acc[mt][nt][r] * sinv[nt]);
      }
    }
}

// ---------------- K2a: per-(b,c,chunk) local 64-bin histogram ------------------
__global__ __launch_bounds__(64) void k_hist(const int* __restrict__ idx,
                                             const float* __restrict__ P,
                                             float* __restrict__ hist) {
  const int ch = blockIdx.x;
  const int c  = blockIdx.y;
  const int b  = blockIdx.z;
  const int lane = threadIdx.x;
  const int bc = b * 64 + c;
  const float* __restrict__ prow = P + (size_t)bc * LSEQ + ch * CS;
  const int* __restrict__ irow = idx + b * LSEQ + ch * CS;
  float bin = 0.f;
#pragma unroll 8
  for (int s = 0; s < CS; ++s) {
    bin += (lane == irow[s]) ? prow[s] : 0.f;
  }
  hist[((size_t)bc * NC + ch) * 64 + lane] = bin;
}

// ---------------- K2b: in-place exclusive scan across chunks -------------------
__global__ __launch_bounds__(64) void k_chunkscan(float* __restrict__ hist) {
  const int bc = blockIdx.x;
  const int lane = threadIdx.x;
  float* h = hist + (size_t)bc * NC * 64 + lane;
  float run = 0.f;
#pragma unroll
  for (int i = 0; i < NC; ++i) {
    const float v = h[i * 64];
    h[i * 64] = run;
    run += v;
  }
}

// ---------------- K2c: per-(b,t) emission --------------------------------------
__global__ __launch_bounds__(64) void k_emit(const int* __restrict__ idx,
                                             const float* __restrict__ P,
                                             const float* __restrict__ hist,
                                             const float* __restrict__ Wv,
                                             float* __restrict__ out) {
  const int t = blockIdx.x;
  const int b = blockIdx.y;
  const int lane = threadIdx.x;
  const int c = idx[b * LSEQ + t];            // uniform
  const int bc = b * 64 + c;
  const int ch = t / CS;
  float bin = hist[((size_t)bc * NC + ch) * 64 + lane];
  const float* __restrict__ prow = P + (size_t)bc * LSEQ;
  const int* __restrict__ irow = idx + b * LSEQ;
#pragma unroll 4
  for (int s = ch * CS; s <= t; ++s) {
    bin += (lane == irow[s]) ? prow[s] : 0.f;
  }
  float z = bin;
#pragma unroll
  for (int d = 1; d < 64; d <<= 1) z += __shfl_xor(z, d);
  out[((size_t)(b * LSEQ + t)) * 64 + lane] = Wv[0] * bin / z;
}

extern "C" void kernel_launch(void* const* d_in, const int* in_sizes, int n_in,
                              void* d_out, int out_size, void* d_ws, size_t ws_size,
                              hipStream_t stream) {
  const int* idx     = (const int*)d_in[0];     // [16, 2048]
  const float* Wq    = (const float*)d_in[1];   // [64, 64]
  const float* Wv    = (const float*)d_in[2];   // [64, 64] (only [0,0] used)
  const float* v_emb = (const float*)d_in[3];   // [2048, 1]
  float* out = (float*)d_out;                   // [16, 2048, 64] fp32

  // workspace: S[2048] f32 | P[1024*2048] f32 | hist[1024*16*64] f32 |
  //            Ebf[2048] bf16 | Agr[16*64*2048] bf16   (~25.3 MB)
  float* S = (float*)d_ws;
  float* P = S + LSEQ;
  float* hist = P + (size_t)NB * NV * LSEQ;
  unsigned short* Ebf = (unsigned short*)(hist + (size_t)NB * NV * NC * 64);
  unsigned short* Agr = Ebf + LSEQ;

  k_prep<<<1, 64, 0, stream>>>(v_emb, Ebf, S);
  k_gather<<<NB * 8, 256, 0, stream>>>(idx, Wq, Agr);
  k_gemm<<<dim3(16, NB), 256, 0, stream>>>(Agr, Ebf, S, P);
  k_hist<<<dim3(NC, NV, NB), 64, 0, stream>>>(idx, P, hist);
  k_chunkscan<<<NB * NV, 64, 0, stream>>>(hist);
  k_emit<<<dim3(LSEQ, NB), 64, 0, stream>>>(idx, P, hist, Wv, out);
}

// Round 5
// 177.982 us; speedup vs baseline: 2.3067x; 1.5204x over previous
//
#include <hip/hip_runtime.h>

// B=16, L=2048, V=64.
// Algebraic reduction (e is one-hot):
//   E[d] = exp(v_emb[d]); S[t] = prefix_sum(E)[t]
//   F[b,c,s] = sum_{k<=s} E[s-k] * Wq[idx[b,k], c]            (causal Toeplitz GEMM)
//   P[b,c,s] = exp(F[b,c,s] / S[s])                           (softmax w/o max; scores tiny)
//   out[b,t,v] = Wv00 * (sum_{s<=t, idx[b,s]==v} P[b,c_t,s]) / (sum_{s<=t} P[b,c_t,s]),  c_t = idx[b,t]
//
// GEMM: bf16 MFMA 16x16x32, K reversed so the Toeplitz operand is k-contiguous
// (two shifted LDS copies solve odd/even alignment); A pre-gathered to global.
// Scan phase: coalesced lane loads + readlane-broadcast 64-bin histogram
// (no wave-uniform scalar-load walks — that was the 108us k_hist / 255us k_scan
// disease). hist+chunkscan fused; emit masks invalid lanes before broadcast.

#define LSEQ 2048
#define NB 16
#define NV 64
#define CS 64             // scan chunk size
#define NC (LSEQ / CS)    // 32 chunks

typedef __attribute__((ext_vector_type(8))) short bf16x8;
typedef __attribute__((ext_vector_type(4))) float f32x4;

__device__ __forceinline__ unsigned short f2bf(float f) {   // RNE float->bf16
  unsigned int u = __float_as_uint(f);
  return (unsigned short)((u + 0x7FFFu + ((u >> 16) & 1u)) >> 16);
}

__device__ __forceinline__ float rdlane_f(float v, int j) {
  return __uint_as_float(__builtin_amdgcn_readlane(__float_as_uint(v), j));
}

// ---------------- K0: Ebf = bf16(exp(v_emb)), S = inclusive prefix sum (fp32) --
__global__ __launch_bounds__(64) void k_prep(const float* __restrict__ v_emb,
                                             unsigned short* __restrict__ Ebf,
                                             float* __restrict__ S) {
  const int lane = threadIdx.x;          // each lane owns 32 contiguous elems
  const int base = lane * 32;
  float e[32];
  float run = 0.f;
#pragma unroll
  for (int i = 0; i < 32; ++i) { e[i] = expf(v_emb[base + i]); run += e[i]; }
  float incl = run;
#pragma unroll
  for (int d = 1; d < 64; d <<= 1) {
    float up = __shfl_up(incl, d);
    if (lane >= d) incl += up;
  }
  float acc = incl - run;  // exclusive prefix of this lane's chunk
#pragma unroll
  for (int i = 0; i < 32; ++i) {
    acc += e[i];
    Ebf[base + i] = f2bf(e[i]);
    S[base + i] = acc;
  }
}

// ---------------- K0b: Agr[b][c][k''] = bf16(Wq[idx[b,2047-k'']][c]) -----------
__global__ __launch_bounds__(256) void k_gather(const int* __restrict__ idx,
                                                const float* __restrict__ Wq,
                                                unsigned short* __restrict__ Agr) {
  const int b = blockIdx.x >> 3;
  const int tile = blockIdx.x & 7;
  const int w = threadIdx.x >> 6;
  const int lane = threadIdx.x & 63;
  const int kbase = tile * 256 + w * 64;
#pragma unroll
  for (int r = 0; r < 8; ++r) {
    const int k8 = kbase + r * 8;
    unsigned short v[8];
#pragma unroll
    for (int j = 0; j < 8; ++j) {
      const int ii = idx[b * LSEQ + (2047 - (k8 + j))];   // wave-uniform
      v[j] = f2bf(Wq[ii * 64 + lane]);                    // coalesced row read
    }
    uint4 st;
    st.x = (unsigned int)v[0] | ((unsigned int)v[1] << 16);
    st.y = (unsigned int)v[2] | ((unsigned int)v[3] << 16);
    st.z = (unsigned int)v[4] | ((unsigned int)v[5] << 16);
    st.w = (unsigned int)v[6] | ((unsigned int)v[7] << 16);
    *(uint4*)(Agr + ((size_t)(b * 64 + lane)) * LSEQ + k8) = st;
  }
}

// ---------------- K1: MFMA GEMM -> P[(b*64+c)][s] = exp(F/S[s]) ----------------
__global__ __launch_bounds__(256) void k_gemm(const unsigned short* __restrict__ Agr,
                                              const unsigned short* __restrict__ Ebf,
                                              const float* __restrict__ S,
                                              float* __restrict__ P) {
  __shared__ unsigned short GL0[2208];   // GL0[i] = GLv(i)
  __shared__ unsigned short GL1[2176];   // GL1[i] = GLv(i+1)

  const int b  = blockIdx.y;
  const int bn = 15 - (int)blockIdx.x;       // heavy (long-K) blocks first
  const int n0 = bn * 128;
  const int tid = threadIdx.x;
  const int w = tid >> 6;
  const int lane = tid & 63;
  const int quad = lane >> 4;
  const int lm = lane & 15;

  for (int i = tid; i < 2208; i += 256) {
    const int e = i - 127;
    GL0[i] = (e >= 0 && e < LSEQ) ? Ebf[e] : (unsigned short)0;
  }
  for (int i = tid; i < 2176; i += 256) {
    const int e = i + 1 - 127;
    GL1[i] = (e >= 0 && e < LSEQ) ? Ebf[e] : (unsigned short)0;
  }
  __syncthreads();

  f32x4 acc[4][2];
#pragma unroll
  for (int mt = 0; mt < 4; ++mt)
#pragma unroll
    for (int nt = 0; nt < 2; ++nt) acc[mt][nt] = (f32x4){0.f, 0.f, 0.f, 0.f};

  const int nbase = n0 + w * 32;
  const unsigned short* ap[4];
#pragma unroll
  for (int mt = 0; mt < 4; ++mt)
    ap[mt] = Agr + ((size_t)(b * 64 + mt * 16 + lm)) * LSEQ;
  int s0[2];
#pragma unroll
  for (int nt = 0; nt < 2; ++nt) s0[nt] = nbase + nt * 16 + lm - 1920;

  const int kstart = 2048 - (n0 + 128);
#pragma unroll 2
  for (int k = kstart; k < 2048; k += 32) {
    const int kq = k + quad * 8;
    union { uint4 u; bf16x8 v; } a[4];
#pragma unroll
    for (int mt = 0; mt < 4; ++mt) a[mt].u = *(const uint4*)(ap[mt] + kq);
    union { unsigned int u[4]; bf16x8 v; } bb[2];
#pragma unroll
    for (int nt = 0; nt < 2; ++nt) {
      const int s = s0[nt] + kq;
      const unsigned int* base = (s & 1) ? (const unsigned int*)GL1
                                         : (const unsigned int*)GL0;
      const int off = s >> 1;
      bb[nt].u[0] = base[off + 0];
      bb[nt].u[1] = base[off + 1];
      bb[nt].u[2] = base[off + 2];
      bb[nt].u[3] = base[off + 3];
    }
#pragma unroll
    for (int mt = 0; mt < 4; ++mt)
#pragma unroll
      for (int nt = 0; nt < 2; ++nt)
        acc[mt][nt] = __builtin_amdgcn_mfma_f32_16x16x32_bf16(a[mt].v, bb[nt].v,
                                                              acc[mt][nt], 0, 0, 0);
  }

  float sinv[2];
#pragma unroll
  for (int nt = 0; nt < 2; ++nt) sinv[nt] = 1.0f / S[nbase + nt * 16 + lm];
#pragma unroll
  for (int mt = 0; mt < 4; ++mt)
#pragma unroll
    for (int nt = 0; nt < 2; ++nt) {
      const int sidx = nbase + nt * 16 + lm;
#pragma unroll
      for (int r = 0; r < 4; ++r) {
        const int c = mt * 16 + quad * 4 + r;
        P[((size_t)(b * 64 + c)) * LSEQ + sidx] = __expf(acc[mt][nt][r] * sinv[nt]);
      }
    }
}

// ---------------- K2: fused per-(b,c) histogram + exclusive chunk scan ---------
// One wave per (b,c). For each 64-chunk: coalesced lane loads of p/idx, then
// 64-step readlane broadcast into per-lane bin (lane = v). hist[bc][ch][v]
// stores the EXCLUSIVE prefix (before chunk ch). 4 accumulators break the
// add dependency chain; next chunk prefetched before the broadcast loop.
__global__ __launch_bounds__(64) void k_histscan(const int* __restrict__ idx,
                                                 const float* __restrict__ P,
                                                 float* __restrict__ hist) {
  const int bc = blockIdx.x;      // b*64 + c
  const int b = bc >> 6;
  const int lane = threadIdx.x;
  const float* __restrict__ prow = P + (size_t)bc * LSEQ;
  const int* __restrict__ irow = idx + b * LSEQ;
  float* __restrict__ hrow = hist + (size_t)bc * NC * 64 + lane;

  float run = 0.f;
  float p = prow[lane];
  int ii = irow[lane];
  for (int ch = 0; ch < NC; ++ch) {
    hrow[ch * 64] = run;                      // exclusive boundary
    float pn = 0.f; int in_ = 0;
    if (ch + 1 < NC) {                        // prefetch next chunk
      pn = prow[(ch + 1) * 64 + lane];
      in_ = irow[(ch + 1) * 64 + lane];
    }
    float t0 = 0.f, t1 = 0.f, t2 = 0.f, t3 = 0.f;
#pragma unroll
    for (int j = 0; j < 64; j += 4) {
      { const float pj = rdlane_f(p, j + 0); const int ij = __builtin_amdgcn_readlane(ii, j + 0);
        t0 += (lane == ij) ? pj : 0.f; }
      { const float pj = rdlane_f(p, j + 1); const int ij = __builtin_amdgcn_readlane(ii, j + 1);
        t1 += (lane == ij) ? pj : 0.f; }
      { const float pj = rdlane_f(p, j + 2); const int ij = __builtin_amdgcn_readlane(ii, j + 2);
        t2 += (lane == ij) ? pj : 0.f; }
      { const float pj = rdlane_f(p, j + 3); const int ij = __builtin_amdgcn_readlane(ii, j + 3);
        t3 += (lane == ij) ? pj : 0.f; }
    }
    run += (t0 + t1) + (t2 + t3);
    p = pn; ii = in_;
  }
}

// ---------------- K3: per-(b,t) emission ---------------------------------------
// Coalesced chunk loads; invalid lanes (s>t) zeroed BEFORE the broadcast loop.
__global__ __launch_bounds__(64) void k_emit(const int* __restrict__ idx,
                                             const float* __restrict__ P,
                                             const float* __restrict__ hist,
                                             const float* __restrict__ Wv,
                                             float* __restrict__ out) {
  const int t = blockIdx.x;
  const int b = blockIdx.y;
  const int lane = threadIdx.x;
  const int c = idx[b * LSEQ + t];            // uniform
  const int bc = b * 64 + c;
  const int ch = t >> 6;                      // CS == 64
  const int s0 = ch * 64;
  const int rel = t - s0;

  float p = P[(size_t)bc * LSEQ + s0 + lane];
  const int ii = idx[b * LSEQ + s0 + lane];
  p = (lane <= rel) ? p : 0.f;                // causal mask before broadcast

  float bin = hist[((size_t)bc * NC + ch) * 64 + lane];
  float t0 = 0.f, t1 = 0.f, t2 = 0.f, t3 = 0.f;
#pragma unroll
  for (int j = 0; j < 64; j += 4) {
    { const float pj = rdlane_f(p, j + 0); const int ij = __builtin_amdgcn_readlane(ii, j + 0);
      t0 += (lane == ij) ? pj : 0.f; }
    { const float pj = rdlane_f(p, j + 1); const int ij = __builtin_amdgcn_readlane(ii, j + 1);
      t1 += (lane == ij) ? pj : 0.f; }
    { const float pj = rdlane_f(p, j + 2); const int ij = __builtin_amdgcn_readlane(ii, j + 2);
      t2 += (lane == ij) ? pj : 0.f; }
    { const float pj = rdlane_f(p, j + 3); const int ij = __builtin_amdgcn_readlane(ii, j + 3);
      t3 += (lane == ij) ? pj : 0.f; }
  }
  bin += (t0 + t1) + (t2 + t3);

  float z = bin;
#pragma unroll
  for (int d = 1; d < 64; d <<= 1) z += __shfl_xor(z, d);
  out[((size_t)(b * LSEQ + t)) * 64 + lane] = Wv[0] * bin / z;
}

extern "C" void kernel_launch(void* const* d_in, const int* in_sizes, int n_in,
                              void* d_out, int out_size, void* d_ws, size_t ws_size,
                              hipStream_t stream) {
  const int* idx     = (const int*)d_in[0];     // [16, 2048]
  const float* Wq    = (const float*)d_in[1];   // [64, 64]
  const float* Wv    = (const float*)d_in[2];   // [64, 64] (only [0,0] used)
  const float* v_emb = (const float*)d_in[3];   // [2048, 1]
  float* out = (float*)d_out;                   // [16, 2048, 64] fp32

  // workspace: S[2048] f32 | P[1024*2048] f32 | hist[1024*32*64] f32 |
  //            Ebf[2048] bf16 | Agr[16*64*2048] bf16   (~20.5 MB)
  float* S = (float*)d_ws;
  float* P = S + LSEQ;
  float* hist = P + (size_t)NB * NV * LSEQ;
  unsigned short* Ebf = (unsigned short*)(hist + (size_t)NB * NV * NC * 64);
  unsigned short* Agr = Ebf + LSEQ;

  k_prep<<<1, 64, 0, stream>>>(v_emb, Ebf, S);
  k_gather<<<NB * 8, 256, 0, stream>>>(idx, Wq, Agr);
  k_gemm<<<dim3(16, NB), 256, 0, stream>>>(Agr, Ebf, S, P);
  k_histscan<<<NB * NV, 64, 0, stream>>>(idx, P, hist);
  k_emit<<<dim3(LSEQ, NB), 64, 0, stream>>>(idx, P, hist, Wv, out);
}

// Round 6
// 169.069 us; speedup vs baseline: 2.4283x; 1.0527x over previous
//
#include <hip/hip_runtime.h>

// B=16, L=2048, V=64.
// Algebraic reduction (e is one-hot):
//   E[d] = exp(v_emb[d]); S[t] = prefix_sum(E)[t]
//   F[b,c,s] = sum_{k<=s} E[s-k] * Wq[idx[b,k], c]            (causal Toeplitz GEMM)
//   P[b,c,s] = exp(F[b,c,s] / S[s])                           (softmax w/o max; scores tiny)
//   out[b,t,v] = Wv00 * (sum_{s<=t, idx[b,s]==v} P[b,c_t,s]) / (sum_{s<=t} P[b,c_t,s]),  c_t = idx[b,t]
//
// GEMM: bf16 MFMA 16x16x32, K reversed so the Toeplitz operand is k-contiguous
// (two shifted LDS copies solve odd/even alignment); A pre-gathered to global.
// Scan phase: 64-bin chunk histograms via ONE ds_add_f32 (LDS float atomic)
// per 64 items — replaces the serial readlane broadcast (49.5us -> ~4us).

#define LSEQ 2048
#define NB 16
#define NV 64
#define CS 64             // scan chunk size
#define NC (LSEQ / CS)    // 32 chunks

typedef __attribute__((ext_vector_type(8))) short bf16x8;
typedef __attribute__((ext_vector_type(4))) float f32x4;

__device__ __forceinline__ unsigned short f2bf(float f) {   // RNE float->bf16
  unsigned int u = __float_as_uint(f);
  return (unsigned short)((u + 0x7FFFu + ((u >> 16) & 1u)) >> 16);
}

// ---------------- K0: Ebf = bf16(exp(v_emb)), S = inclusive prefix sum (fp32) --
__global__ __launch_bounds__(64) void k_prep(const float* __restrict__ v_emb,
                                             unsigned short* __restrict__ Ebf,
                                             float* __restrict__ S) {
  const int lane = threadIdx.x;          // each lane owns 32 contiguous elems
  const int base = lane * 32;
  float e[32];
  float run = 0.f;
#pragma unroll
  for (int i = 0; i < 32; ++i) { e[i] = expf(v_emb[base + i]); run += e[i]; }
  float incl = run;
#pragma unroll
  for (int d = 1; d < 64; d <<= 1) {
    float up = __shfl_up(incl, d);
    if (lane >= d) incl += up;
  }
  float acc = incl - run;  // exclusive prefix of this lane's chunk
#pragma unroll
  for (int i = 0; i < 32; ++i) {
    acc += e[i];
    Ebf[base + i] = f2bf(e[i]);
    S[base + i] = acc;
  }
}

// ---------------- K0b: Agr[b][c][k''] = bf16(Wq[idx[b,2047-k'']][c]) -----------
__global__ __launch_bounds__(256) void k_gather(const int* __restrict__ idx,
                                                const float* __restrict__ Wq,
                                                unsigned short* __restrict__ Agr) {
  const int b = blockIdx.x >> 3;
  const int tile = blockIdx.x & 7;
  const int w = threadIdx.x >> 6;
  const int lane = threadIdx.x & 63;
  const int kbase = tile * 256 + w * 64;
#pragma unroll
  for (int r = 0; r < 8; ++r) {
    const int k8 = kbase + r * 8;
    unsigned short v[8];
#pragma unroll
    for (int j = 0; j < 8; ++j) {
      const int ii = idx[b * LSEQ + (2047 - (k8 + j))];   // wave-uniform
      v[j] = f2bf(Wq[ii * 64 + lane]);                    // coalesced row read
    }
    uint4 st;
    st.x = (unsigned int)v[0] | ((unsigned int)v[1] << 16);
    st.y = (unsigned int)v[2] | ((unsigned int)v[3] << 16);
    st.z = (unsigned int)v[4] | ((unsigned int)v[5] << 16);
    st.w = (unsigned int)v[6] | ((unsigned int)v[7] << 16);
    *(uint4*)(Agr + ((size_t)(b * 64 + lane)) * LSEQ + k8) = st;
  }
}

// ---------------- K1: MFMA GEMM -> P[(b*64+c)][s] = exp(F/S[s]) ----------------
// 512 blocks (2/CU): block = (b, 64-wide n-tile); wave = M64 (4 m-tiles) x N16.
__global__ __launch_bounds__(256) void k_gemm(const unsigned short* __restrict__ Agr,
                                              const unsigned short* __restrict__ Ebf,
                                              const float* __restrict__ S,
                                              float* __restrict__ P) {
  __shared__ unsigned short GL0[2208];   // GL0[i] = GLv(i)
  __shared__ unsigned short GL1[2176];   // GL1[i] = GLv(i+1)
  // GLv(i) = (127<=i<2175) ? E[i-127] : 0

  const int b  = blockIdx.y;
  const int bn = 31 - (int)blockIdx.x;       // heavy (long-K) blocks first
  const int n0 = bn * 64;
  const int tid = threadIdx.x;
  const int w = tid >> 6;
  const int lane = tid & 63;
  const int quad = lane >> 4;
  const int lm = lane & 15;

  for (int i = tid; i < 2208; i += 256) {
    const int e = i - 127;
    GL0[i] = (e >= 0 && e < LSEQ) ? Ebf[e] : (unsigned short)0;
  }
  for (int i = tid; i < 2176; i += 256) {
    const int e = i + 1 - 127;
    GL1[i] = (e >= 0 && e < LSEQ) ? Ebf[e] : (unsigned short)0;
  }
  __syncthreads();

  f32x4 acc[4];
#pragma unroll
  for (int mt = 0; mt < 4; ++mt) acc[mt] = (f32x4){0.f, 0.f, 0.f, 0.f};

  const int nbase = n0 + w * 16;             // wave's 16-wide n slice
  const unsigned short* ap[4];
#pragma unroll
  for (int mt = 0; mt < 4; ++mt)
    ap[mt] = Agr + ((size_t)(b * 64 + mt * 16 + lm)) * LSEQ;
  const int s0 = nbase + lm - 1920;

  const int kstart = 2048 - (n0 + 64);       // causal K extent (k'' reversed)
#pragma unroll 2
  for (int k = kstart; k < 2048; k += 32) {
    const int kq = k + quad * 8;
    union { uint4 u; bf16x8 v; } a[4];
#pragma unroll
    for (int mt = 0; mt < 4; ++mt) a[mt].u = *(const uint4*)(ap[mt] + kq);
    union { unsigned int u[4]; bf16x8 v; } bb;
    {
      const int s = s0 + kq;                           // frag start elem (>=0)
      const unsigned int* base = (s & 1) ? (const unsigned int*)GL1
                                         : (const unsigned int*)GL0;
      const int off = s >> 1;
      bb.u[0] = base[off + 0];
      bb.u[1] = base[off + 1];
      bb.u[2] = base[off + 2];
      bb.u[3] = base[off + 3];
    }
#pragma unroll
    for (int mt = 0; mt < 4; ++mt)
      acc[mt] = __builtin_amdgcn_mfma_f32_16x16x32_bf16(a[mt].v, bb.v, acc[mt], 0, 0, 0);
  }

  // epilogue: C/D layout col(s)=lane&15, row(c)=quad*4+reg
  const float sinv = 1.0f / S[nbase + lm];
#pragma unroll
  for (int mt = 0; mt < 4; ++mt) {
#pragma unroll
    for (int r = 0; r < 4; ++r) {
      const int c = mt * 16 + quad * 4 + r;
      P[((size_t)(b * 64 + c)) * LSEQ + nbase + lm] = __expf(acc[mt][r] * sinv);
    }
  }
}

// ---------------- K2: per-(b,c,chunk) 64-bin histogram via ds_add_f32 ----------
// One wave per (b,c,ch); 4 waves/block share the idx chunk implicitly.
__global__ __launch_bounds__(256) void k_chist(const int* __restrict__ idx,
                                               const float* __restrict__ P,
                                               float* __restrict__ hist) {
  __shared__ float bins[4][64];
  const int ch = blockIdx.x;      // 0..31
  const int cg = blockIdx.y;      // 0..15
  const int b  = blockIdx.z;      // 0..15
  const int w = threadIdx.x >> 6;
  const int lane = threadIdx.x & 63;
  const int c = cg * 4 + w;
  const int bc = b * 64 + c;
  const int s0 = ch * 64;

  const float p = P[(size_t)bc * LSEQ + s0 + lane];   // coalesced 256B
  const int ii = idx[b * LSEQ + s0 + lane];
  bins[w][lane] = 0.f;
  __syncthreads();
  atomicAdd(&bins[w][ii], p);                         // one ds_add_f32
  __syncthreads();
  hist[((size_t)bc * NC + ch) * 64 + lane] = bins[w][lane];
}

// ---------------- K2b: in-place exclusive scan across chunks -------------------
// All 32 loads issued up-front (independent), then register scan + stores.
__global__ __launch_bounds__(64) void k_cscan(float* __restrict__ hist) {
  const int bc = blockIdx.x;
  const int lane = threadIdx.x;
  float* h = hist + (size_t)bc * NC * 64 + lane;
  float v[NC];
#pragma unroll
  for (int ch = 0; ch < NC; ++ch) v[ch] = h[ch * 64];
  float run = 0.f;
#pragma unroll
  for (int ch = 0; ch < NC; ++ch) {
    const float x = v[ch];
    h[ch * 64] = run;
    run += x;
  }
}

// ---------------- K3: per-(b,t) emission (ds_add histogram of masked chunk) ----
__global__ __launch_bounds__(256) void k_emit(const int* __restrict__ idx,
                                              const float* __restrict__ P,
                                              const float* __restrict__ hist,
                                              const float* __restrict__ Wv,
                                              float* __restrict__ out) {
  __shared__ float bins[4][64];
  const int tg = blockIdx.x;      // t-group: t = tg*4 + w
  const int b  = blockIdx.y;
  const int w = threadIdx.x >> 6;
  const int lane = threadIdx.x & 63;
  const int t = tg * 4 + w;
  const int c = idx[b * LSEQ + t];            // wave-uniform
  const int bc = b * 64 + c;
  const int ch = t >> 6;                      // CS == 64
  const int s0 = ch * 64;
  const int rel = t - s0;

  float p = P[(size_t)bc * LSEQ + s0 + lane];
  const int ii = idx[b * LSEQ + s0 + lane];
  p = (lane <= rel) ? p : 0.f;                // causal mask
  bins[w][lane] = 0.f;
  __syncthreads();
  atomicAdd(&bins[w][ii], p);
  __syncthreads();
  float bin = bins[w][lane] + hist[((size_t)bc * NC + ch) * 64 + lane];

  float z = bin;
#pragma unroll
  for (int d = 1; d < 64; d <<= 1) z += __shfl_xor(z, d);
  out[((size_t)(b * LSEQ + t)) * 64 + lane] = Wv[0] * bin / z;
}

extern "C" void kernel_launch(void* const* d_in, const int* in_sizes, int n_in,
                              void* d_out, int out_size, void* d_ws, size_t ws_size,
                              hipStream_t stream) {
  const int* idx     = (const int*)d_in[0];     // [16, 2048]
  const float* Wq    = (const float*)d_in[1];   // [64, 64]
  const float* Wv    = (const float*)d_in[2];   // [64, 64] (only [0,0] used)
  const float* v_emb = (const float*)d_in[3];   // [2048, 1]
  float* out = (float*)d_out;                   // [16, 2048, 64] fp32

  // workspace: S[2048] f32 | P[1024*2048] f32 | hist[1024*32*64] f32 |
  //            Ebf[2048] bf16 | Agr[16*64*2048] bf16   (~20.5 MB)
  float* S = (float*)d_ws;
  float* P = S + LSEQ;
  float* hist = P + (size_t)NB * NV * LSEQ;
  unsigned short* Ebf = (unsigned short*)(hist + (size_t)NB * NV * NC * 64);
  unsigned short* Agr = Ebf + LSEQ;

  k_prep<<<1, 64, 0, stream>>>(v_emb, Ebf, S);
  k_gather<<<NB * 8, 256, 0, stream>>>(idx, Wq, Agr);
  k_gemm<<<dim3(32, NB), 256, 0, stream>>>(Agr, Ebf, S, P);
  k_chist<<<dim3(NC, 16, NB), 256, 0, stream>>>(idx, P, hist);
  k_cscan<<<NB * NV, 64, 0, stream>>>(hist);
  k_emit<<<dim3(LSEQ / 4, NB), 256, 0, stream>>>(idx, P, hist, Wv, out);
}

// Round 7
// 127.414 us; speedup vs baseline: 3.2222x; 1.3269x over previous
//
#include <hip/hip_runtime.h>

// B=16, L=2048, V=64.
// Algebraic reduction (e is one-hot):
//   E[d] = exp(v_emb[d]); S[t] = prefix_sum(E)[t]
//   F[b,c,s] = sum_{k<=s} E[s-k] * Wq[idx[b,k], c]            (causal Toeplitz GEMM)
//   P[b,c,s] = exp(F[b,c,s] / S[s])                           (softmax w/o max; scores tiny)
//   out[b,t,v] = Wv00 * (sum_{s<=t, idx[b,s]==v} P[b,c_t,s]) / (sum_{s<=t} P[b,c_t,s]),  c_t = idx[b,t]
//
// GEMM: bf16 MFMA 16x16x32, K reversed so the Toeplitz operand is k-contiguous.
// R7: k_gemm was latency-bound (62us, MfmaUtil 2.5%, 2 blocks/CU). Now:
// 32-wide n-tiles + 2-way k-split (grid 1024 = 4 blocks/CU, 4 waves/SIMD),
// explicit ping-pong prefetch of A/B frags, A pre-transposed to [b][k8][c][8]
// so frag loads are 256B-contiguous. Scan phase: ds_add_f32 histograms.

#define LSEQ 2048
#define NB 16
#define NV 64
#define CS 64             // scan chunk size
#define NC (LSEQ / CS)    // 32 chunks

typedef __attribute__((ext_vector_type(8))) short bf16x8;
typedef __attribute__((ext_vector_type(4))) float f32x4;

__device__ __forceinline__ unsigned short f2bf(float f) {   // RNE float->bf16
  unsigned int u = __float_as_uint(f);
  return (unsigned short)((u + 0x7FFFu + ((u >> 16) & 1u)) >> 16);
}

// ---------------- K0: gather + (fused) prep ------------------------------------
// Agr[((b*256 + k8)*64 + c)*8 + j] = bf16(Wq[idx[b, 2047-(k8*8+j)]][c])
// Block 0 / wave 0 additionally computes Ebf = bf16(exp(v_emb)) and S = prefix.
__global__ __launch_bounds__(256) void k_gather(const int* __restrict__ idx,
                                                const float* __restrict__ Wq,
                                                const float* __restrict__ v_emb,
                                                unsigned short* __restrict__ Agr,
                                                unsigned short* __restrict__ Ebf,
                                                float* __restrict__ S) {
  const int b = blockIdx.x >> 3;
  const int tile = blockIdx.x & 7;
  const int w = threadIdx.x >> 6;
  const int lane = threadIdx.x & 63;

  if (blockIdx.x == 0 && threadIdx.x < 64) {   // fused k_prep (one wave)
    const int base = lane * 32;
    float e[32];
    float run = 0.f;
#pragma unroll
    for (int i = 0; i < 32; ++i) { e[i] = expf(v_emb[base + i]); run += e[i]; }
    float incl = run;
#pragma unroll
    for (int d = 1; d < 64; d <<= 1) {
      float up = __shfl_up(incl, d);
      if (lane >= d) incl += up;
    }
    float acc = incl - run;
#pragma unroll
    for (int i = 0; i < 32; ++i) {
      acc += e[i];
      Ebf[base + i] = f2bf(e[i]);
      S[base + i] = acc;
    }
  }

  const int k8base = tile * 32 + w * 8;        // this wave's 8 k8-groups
#pragma unroll
  for (int r = 0; r < 8; ++r) {
    const int k8 = k8base + r;
    unsigned short v[8];
#pragma unroll
    for (int j = 0; j < 8; ++j) {
      const int ii = idx[b * LSEQ + (2047 - (k8 * 8 + j))];  // wave-uniform
      v[j] = f2bf(Wq[ii * 64 + lane]);                       // coalesced row read
    }
    uint4 st;
    st.x = (unsigned int)v[0] | ((unsigned int)v[1] << 16);
    st.y = (unsigned int)v[2] | ((unsigned int)v[3] << 16);
    st.z = (unsigned int)v[4] | ((unsigned int)v[5] << 16);
    st.w = (unsigned int)v[6] | ((unsigned int)v[7] << 16);
    *(uint4*)(Agr + ((size_t)(b * 256 + k8) * 64 + lane) * 8) = st;  // 16B/lane coalesced
  }
}

// ---------------- K1: MFMA GEMM -> P[(b*64+c)][s] = exp(F/S[s]) ----------------
// Block = (b, 32-wide n-tile); 4 waves = 2 n-subtiles x 2 k-halves (stride-2
// interleave). Ping-pong prefetch; k-half partials reduced via LDS.
__global__ __launch_bounds__(256) void k_gemm(const unsigned short* __restrict__ Agr,
                                              const unsigned short* __restrict__ Ebf,
                                              const float* __restrict__ S,
                                              float* __restrict__ P) {
  __shared__ unsigned short GL0[2208];   // GL0[i] = GLv(i)
  __shared__ unsigned short GL1[2176];   // GL1[i] = GLv(i+1)
  __shared__ float red[16][64];          // k-half-1 partials [acc idx][tid&63 of waves 2,3... reused per pair]
  __shared__ float red2[16][64];
  // GLv(i) = (127<=i<2175) ? E[i-127] : 0

  const int b  = blockIdx.y;
  const int bn = 63 - (int)blockIdx.x;       // heavy (long-K) blocks first
  const int n0 = bn * 32;
  const int tid = threadIdx.x;
  const int w = tid >> 6;
  const int lane = tid & 63;
  const int quad = lane >> 4;
  const int lm = lane & 15;
  const int nsub = w & 1;                    // n-offset 0 / 16
  const int kh = w >> 1;                     // k-half 0 / 1

  for (int i = tid; i < 2208; i += 256) {
    const int e = i - 127;
    GL0[i] = (e >= 0 && e < LSEQ) ? Ebf[e] : (unsigned short)0;
  }
  for (int i = tid; i < 2176; i += 256) {
    const int e = i + 1 - 127;
    GL1[i] = (e >= 0 && e < LSEQ) ? Ebf[e] : (unsigned short)0;
  }
  __syncthreads();

  f32x4 acc[4];
#pragma unroll
  for (int mt = 0; mt < 4; ++mt) acc[mt] = (f32x4){0.f, 0.f, 0.f, 0.f};

  const int nbase = n0 + nsub * 16;
  const int sbase = nbase + lm - 1920;
  const int kstart = 2048 - (n0 + 32);       // multiple of 32
  const int iters = bn + 1;                  // 32-k steps for this tile
  const unsigned short* __restrict__ abase = Agr + (size_t)b * 256 * 64 * 8;

#define LOAD_FRAGS(IT, A_, B_) do {                                         \
    const int k_ = kstart + (IT) * 32;                                      \
    const int kq8_ = (k_ >> 3) + quad;                                      \
    const unsigned short* ab_ = abase + ((size_t)kq8_ * 64 + lm) * 8;       \
    A_[0].u = *(const uint4*)(ab_ + 0 * 128);                               \
    A_[1].u = *(const uint4*)(ab_ + 1 * 128);                               \
    A_[2].u = *(const uint4*)(ab_ + 2 * 128);                               \
    A_[3].u = *(const uint4*)(ab_ + 3 * 128);                               \
    const int s_ = sbase + k_ + quad * 8;                                   \
    const unsigned int* gb_ = (s_ & 1) ? (const unsigned int*)GL1           \
                                       : (const unsigned int*)GL0;          \
    const int off_ = s_ >> 1;                                               \
    B_.u[0] = gb_[off_ + 0]; B_.u[1] = gb_[off_ + 1];                       \
    B_.u[2] = gb_[off_ + 2]; B_.u[3] = gb_[off_ + 3];                       \
  } while (0)

  union AF { uint4 u; bf16x8 v; };
  union BF { unsigned int u[4]; bf16x8 v; };
  AF a0[4], a1[4];
  BF b0, b1;

  int it = kh;
  bool more = it < iters;
  if (more) LOAD_FRAGS(it, a0, b0);
  while (more) {
    {
      const int itn = it + 2;
      const bool mn = itn < iters;
      if (mn) LOAD_FRAGS(itn, a1, b1);
#pragma unroll
      for (int mt = 0; mt < 4; ++mt)
        acc[mt] = __builtin_amdgcn_mfma_f32_16x16x32_bf16(a0[mt].v, b0.v, acc[mt], 0, 0, 0);
      it = itn; more = mn;
    }
    if (!more) break;
    {
      const int itn = it + 2;
      const bool mn = itn < iters;
      if (mn) LOAD_FRAGS(itn, a0, b0);
#pragma unroll
      for (int mt = 0; mt < 4; ++mt)
        acc[mt] = __builtin_amdgcn_mfma_f32_16x16x32_bf16(a1[mt].v, b1.v, acc[mt], 0, 0, 0);
      it = itn; more = mn;
    }
  }
#undef LOAD_FRAGS

  // reduce k-half 1 into k-half 0 via LDS (lane-contiguous rows: conflict-free)
  if (kh == 1) {
    float (*rd)[64] = nsub ? red2 : red;
#pragma unroll
    for (int mt = 0; mt < 4; ++mt)
#pragma unroll
      for (int r = 0; r < 4; ++r) rd[mt * 4 + r][lane] = acc[mt][r];
  }
  __syncthreads();
  if (kh == 0) {
    float (*rd)[64] = nsub ? red2 : red;
#pragma unroll
    for (int mt = 0; mt < 4; ++mt)
#pragma unroll
      for (int r = 0; r < 4; ++r) acc[mt][r] += rd[mt * 4 + r][lane];

    // epilogue: C/D layout col(s)=lm, row(c)=quad*4+r
    const float sinv = 1.0f / S[nbase + lm];
#pragma unroll
    for (int mt = 0; mt < 4; ++mt) {
#pragma unroll
      for (int r = 0; r < 4; ++r) {
        const int c = mt * 16 + quad * 4 + r;
        P[((size_t)(b * 64 + c)) * LSEQ + nbase + lm] = __expf(acc[mt][r] * sinv);
      }
    }
  }
}

// ---------------- K2: per-(b,c,chunk) 64-bin histogram via ds_add_f32 ----------
__global__ __launch_bounds__(256) void k_chist(const int* __restrict__ idx,
                                               const float* __restrict__ P,
                                               float* __restrict__ hist) {
  __shared__ float bins[4][64];
  const int ch = blockIdx.x;      // 0..31
  const int cg = blockIdx.y;      // 0..15
  const int b  = blockIdx.z;      // 0..15
  const int w = threadIdx.x >> 6;
  const int lane = threadIdx.x & 63;
  const int c = cg * 4 + w;
  const int bc = b * 64 + c;
  const int s0 = ch * 64;

  const float p = P[(size_t)bc * LSEQ + s0 + lane];   // coalesced 256B
  const int ii = idx[b * LSEQ + s0 + lane];
  bins[w][lane] = 0.f;
  __syncthreads();
  atomicAdd(&bins[w][ii], p);                         // one ds_add_f32
  __syncthreads();
  hist[((size_t)bc * NC + ch) * 64 + lane] = bins[w][lane];
}

// ---------------- K2b: in-place exclusive scan across chunks -------------------
__global__ __launch_bounds__(64) void k_cscan(float* __restrict__ hist) {
  const int bc = blockIdx.x;
  const int lane = threadIdx.x;
  float* h = hist + (size_t)bc * NC * 64 + lane;
  float v[NC];
#pragma unroll
  for (int ch = 0; ch < NC; ++ch) v[ch] = h[ch * 64];
  float run = 0.f;
#pragma unroll
  for (int ch = 0; ch < NC; ++ch) {
    const float x = v[ch];
    h[ch * 64] = run;
    run += x;
  }
}

// ---------------- K3: per-(b,t) emission (ds_add histogram of masked chunk) ----
__global__ __launch_bounds__(256) void k_emit(const int* __restrict__ idx,
                                              const float* __restrict__ P,
                                              const float* __restrict__ hist,
                                              const float* __restrict__ Wv,
                                              float* __restrict__ out) {
  __shared__ float bins[4][64];
  const int tg = blockIdx.x;      // t = tg*4 + w
  const int b  = blockIdx.y;
  const int w = threadIdx.x >> 6;
  const int lane = threadIdx.x & 63;
  const int t = tg * 4 + w;
  const int c = idx[b * LSEQ + t];            // wave-uniform
  const int bc = b * 64 + c;
  const int ch = t >> 6;                      // CS == 64
  const int s0 = ch * 64;
  const int rel = t - s0;

  float p = P[(size_t)bc * LSEQ + s0 + lane];
  const int ii = idx[b * LSEQ + s0 + lane];
  p = (lane <= rel) ? p : 0.f;                // causal mask
  bins[w][lane] = 0.f;
  __syncthreads();
  atomicAdd(&bins[w][ii], p);
  __syncthreads();
  float bin = bins[w][lane] + hist[((size_t)bc * NC + ch) * 64 + lane];

  float z = bin;
#pragma unroll
  for (int d = 1; d < 64; d <<= 1) z += __shfl_xor(z, d);
  out[((size_t)(b * LSEQ + t)) * 64 + lane] = Wv[0] * bin / z;
}

extern "C" void kernel_launch(void* const* d_in, const int* in_sizes, int n_in,
                              void* d_out, int out_size, void* d_ws, size_t ws_size,
                              hipStream_t stream) {
  const int* idx     = (const int*)d_in[0];     // [16, 2048]
  const float* Wq    = (const float*)d_in[1];   // [64, 64]
  const float* Wv    = (const float*)d_in[2];   // [64, 64] (only [0,0] used)
  const float* v_emb = (const float*)d_in[3];   // [2048, 1]
  float* out = (float*)d_out;                   // [16, 2048, 64] fp32

  // workspace: S[2048] f32 | P[1024*2048] f32 | hist[1024*32*64] f32 |
  //            Ebf[2048] bf16 | Agr[16*256*64*8] bf16   (~20.5 MB)
  float* S = (float*)d_ws;
  float* P = S + LSEQ;
  float* hist = P + (size_t)NB * NV * LSEQ;
  unsigned short* Ebf = (unsigned short*)(hist + (size_t)NB * NV * NC * 64);
  unsigned short* Agr = Ebf + LSEQ;

  k_gather<<<NB * 8, 256, 0, stream>>>(idx, Wq, v_emb, Agr, Ebf, S);
  k_gemm<<<dim3(64, NB), 256, 0, stream>>>(Agr, Ebf, S, P);
  k_chist<<<dim3(NC, 16, NB), 256, 0, stream>>>(idx, P, hist);
  k_cscan<<<NB * NV, 64, 0, stream>>>(hist);
  k_emit<<<dim3(LSEQ / 4, NB), 256, 0, stream>>>(idx, P, hist, Wv, out);
}

// Round 8
// 124.946 us; speedup vs baseline: 3.2858x; 1.0198x over previous
//
#include <hip/hip_runtime.h>

// B=16, L=2048, V=64.
// Algebraic reduction (e is one-hot):
//   E[d] = exp(v_emb[d]); S[t] = prefix_sum(E)[t]
//   F[b,c,s] = sum_{k<=s} E[s-k] * Wq[idx[b,k], c]            (causal Toeplitz GEMM)
//   P[b,c,s] = exp(F[b,c,s] / S[s])                           (softmax w/o max; scores tiny)
//   out[b,t,v] = Wv00 * (sum_{s<=t, idx[b,s]==v} P[b,c_t,s]) / (sum_{s<=t} P[b,c_t,s]),  c_t = idx[b,t]
//
// R8: gemm gets a 3-buffer rotating pipeline (prefetch distance 2 wave-iters)
// so vmcnt waits are covered by 4 waves/SIMD of MFMA issue; k_cscan folded
// into k_emit (raw chunk histograms, emit sums its own prefix); gather 2x grid.

#define LSEQ 2048
#define NB 16
#define NV 64
#define CS 64             // scan chunk size
#define NC (LSEQ / CS)    // 32 chunks

typedef __attribute__((ext_vector_type(8))) short bf16x8;
typedef __attribute__((ext_vector_type(4))) float f32x4;

__device__ __forceinline__ unsigned short f2bf(float f) {   // RNE float->bf16
  unsigned int u = __float_as_uint(f);
  return (unsigned short)((u + 0x7FFFu + ((u >> 16) & 1u)) >> 16);
}

// ---------------- K0: gather + (fused) prep ------------------------------------
// Agr[((b*256 + k8)*64 + c)*8 + j] = bf16(Wq[idx[b, 2047-(k8*8+j)]][c])
__global__ __launch_bounds__(256) void k_gather(const int* __restrict__ idx,
                                                const float* __restrict__ Wq,
                                                const float* __restrict__ v_emb,
                                                unsigned short* __restrict__ Agr,
                                                unsigned short* __restrict__ Ebf,
                                                float* __restrict__ S) {
  const int b = blockIdx.x >> 4;
  const int tile = blockIdx.x & 15;
  const int w = threadIdx.x >> 6;
  const int lane = threadIdx.x & 63;

  if (blockIdx.x == 0 && threadIdx.x < 64) {   // fused prep (one wave)
    const int base = lane * 32;
    float e[32];
    float run = 0.f;
#pragma unroll
    for (int i = 0; i < 32; ++i) { e[i] = expf(v_emb[base + i]); run += e[i]; }
    float incl = run;
#pragma unroll
    for (int d = 1; d < 64; d <<= 1) {
      float up = __shfl_up(incl, d);
      if (lane >= d) incl += up;
    }
    float acc = incl - run;
#pragma unroll
    for (int i = 0; i < 32; ++i) {
      acc += e[i];
      Ebf[base + i] = f2bf(e[i]);
      S[base + i] = acc;
    }
  }

  const int k8base = tile * 16 + w * 4;        // this wave's 4 k8-groups
#pragma unroll
  for (int r = 0; r < 4; ++r) {
    const int k8 = k8base + r;
    unsigned short v[8];
#pragma unroll
    for (int j = 0; j < 8; ++j) {
      const int ii = idx[b * LSEQ + (2047 - (k8 * 8 + j))];  // wave-uniform
      v[j] = f2bf(Wq[ii * 64 + lane]);                       // coalesced row read
    }
    uint4 st;
    st.x = (unsigned int)v[0] | ((unsigned int)v[1] << 16);
    st.y = (unsigned int)v[2] | ((unsigned int)v[3] << 16);
    st.z = (unsigned int)v[4] | ((unsigned int)v[5] << 16);
    st.w = (unsigned int)v[6] | ((unsigned int)v[7] << 16);
    *(uint4*)(Agr + ((size_t)(b * 256 + k8) * 64 + lane) * 8) = st;  // 16B/lane coalesced
  }
}

// ---------------- K1: MFMA GEMM -> P[(b*64+c)][s] = exp(F/S[s]) ----------------
// Block = (b, 32-wide n-tile); 4 waves = 2 n-subtiles x 2 k-halves.
// 3-buffer rotating pipeline, prefetch distance = 2 wave-iters.
__global__ __launch_bounds__(256) void k_gemm(const unsigned short* __restrict__ Agr,
                                              const unsigned short* __restrict__ Ebf,
                                              const float* __restrict__ S,
                                              float* __restrict__ P) {
  __shared__ unsigned short GL0[2208];   // GL0[i] = GLv(i)
  __shared__ unsigned short GL1[2176];   // GL1[i] = GLv(i+1)
  __shared__ float red[16][64];
  __shared__ float red2[16][64];
  // GLv(i) = (127<=i<2175) ? E[i-127] : 0

  const int b  = blockIdx.y;
  const int bn = 63 - (int)blockIdx.x;       // heavy (long-K) blocks first
  const int n0 = bn * 32;
  const int tid = threadIdx.x;
  const int w = tid >> 6;
  const int lane = tid & 63;
  const int quad = lane >> 4;
  const int lm = lane & 15;
  const int nsub = w & 1;                    // n-offset 0 / 16
  const int kh = w >> 1;                     // k-half 0 / 1

  for (int i = tid; i < 2208; i += 256) {
    const int e = i - 127;
    GL0[i] = (e >= 0 && e < LSEQ) ? Ebf[e] : (unsigned short)0;
  }
  for (int i = tid; i < 2176; i += 256) {
    const int e = i + 1 - 127;
    GL1[i] = (e >= 0 && e < LSEQ) ? Ebf[e] : (unsigned short)0;
  }
  __syncthreads();

  f32x4 acc[4];
#pragma unroll
  for (int mt = 0; mt < 4; ++mt) acc[mt] = (f32x4){0.f, 0.f, 0.f, 0.f};

  const int nbase = n0 + nsub * 16;
  const int sbase = nbase + lm - 1920;
  const int kstart = 2048 - (n0 + 32);       // multiple of 32
  const int iters = bn + 1;                  // total 32-k steps for this tile
  const unsigned short* __restrict__ abase = Agr + (size_t)b * 256 * 64 * 8;

  union AF { uint4 u; bf16x8 v; };
  union BF { unsigned int u[4]; bf16x8 v; };
  AF a[3][4];
  BF bb[3];

#define LOAD_FRAGS(J_, SL) do {                                             \
    const int k_ = kstart + (kh + 2 * (J_)) * 32;                           \
    const int kq8_ = (k_ >> 3) + quad;                                      \
    const unsigned short* ab_ = abase + ((size_t)kq8_ * 64 + lm) * 8;       \
    a[SL][0].u = *(const uint4*)(ab_ + 0 * 128);                            \
    a[SL][1].u = *(const uint4*)(ab_ + 1 * 128);                            \
    a[SL][2].u = *(const uint4*)(ab_ + 2 * 128);                            \
    a[SL][3].u = *(const uint4*)(ab_ + 3 * 128);                            \
    const int s_ = sbase + k_ + quad * 8;                                   \
    const unsigned int* gb_ = (s_ & 1) ? (const unsigned int*)GL1           \
                                       : (const unsigned int*)GL0;          \
    const int off_ = s_ >> 1;                                               \
    bb[SL].u[0] = gb_[off_ + 0]; bb[SL].u[1] = gb_[off_ + 1];               \
    bb[SL].u[2] = gb_[off_ + 2]; bb[SL].u[3] = gb_[off_ + 3];               \
  } while (0)

#define MFMA4(SL) do {                                                      \
    acc[0] = __builtin_amdgcn_mfma_f32_16x16x32_bf16(a[SL][0].v, bb[SL].v, acc[0], 0, 0, 0); \
    acc[1] = __builtin_amdgcn_mfma_f32_16x16x32_bf16(a[SL][1].v, bb[SL].v, acc[1], 0, 0, 0); \
    acc[2] = __builtin_amdgcn_mfma_f32_16x16x32_bf16(a[SL][2].v, bb[SL].v, acc[2], 0, 0, 0); \
    acc[3] = __builtin_amdgcn_mfma_f32_16x16x32_bf16(a[SL][3].v, bb[SL].v, acc[3], 0, 0, 0); \
  } while (0)

  const int J = (iters > kh) ? ((iters - kh + 1) >> 1) : 0;  // wave-iters
  if (J > 0) {
    LOAD_FRAGS(0, 0);
    if (J > 1) LOAD_FRAGS(1, 1);
    int j = 0;
    while (true) {
      if (j + 2 < J) LOAD_FRAGS(j + 2, 2);
      MFMA4(0);
      if (++j >= J) break;
      if (j + 2 < J) LOAD_FRAGS(j + 2, 0);
      MFMA4(1);
      if (++j >= J) break;
      if (j + 2 < J) LOAD_FRAGS(j + 2, 1);
      MFMA4(2);
      if (++j >= J) break;
    }
  }
#undef LOAD_FRAGS
#undef MFMA4

  // reduce k-half 1 into k-half 0 via LDS (lane-contiguous rows: conflict-free)
  if (kh == 1) {
    float (*rd)[64] = nsub ? red2 : red;
#pragma unroll
    for (int mt = 0; mt < 4; ++mt)
#pragma unroll
      for (int r = 0; r < 4; ++r) rd[mt * 4 + r][lane] = acc[mt][r];
  }
  __syncthreads();
  if (kh == 0) {
    float (*rd)[64] = nsub ? red2 : red;
#pragma unroll
    for (int mt = 0; mt < 4; ++mt)
#pragma unroll
      for (int r = 0; r < 4; ++r) acc[mt][r] += rd[mt * 4 + r][lane];

    // epilogue: C/D layout col(s)=lm, row(c)=quad*4+r
    const float sinv = 1.0f / S[nbase + lm];
#pragma unroll
    for (int mt = 0; mt < 4; ++mt) {
#pragma unroll
      for (int r = 0; r < 4; ++r) {
        const int c = mt * 16 + quad * 4 + r;
        P[((size_t)(b * 64 + c)) * LSEQ + nbase + lm] = __expf(acc[mt][r] * sinv);
      }
    }
  }
}

// ---------------- K2: per-(b,c,chunk) 64-bin histogram via ds_add_f32 ----------
__global__ __launch_bounds__(256) void k_chist(const int* __restrict__ idx,
                                               const float* __restrict__ P,
                                               float* __restrict__ hist) {
  __shared__ float bins[4][64];
  const int ch = blockIdx.x;      // 0..31
  const int cg = blockIdx.y;      // 0..15
  const int b  = blockIdx.z;      // 0..15
  const int w = threadIdx.x >> 6;
  const int lane = threadIdx.x & 63;
  const int c = cg * 4 + w;
  const int bc = b * 64 + c;
  const int s0 = ch * 64;

  const float p = P[(size_t)bc * LSEQ + s0 + lane];   // coalesced 256B
  const int ii = idx[b * LSEQ + s0 + lane];
  bins[w][lane] = 0.f;
  __syncthreads();
  atomicAdd(&bins[w][ii], p);                         // one ds_add_f32
  __syncthreads();
  hist[((size_t)bc * NC + ch) * 64 + lane] = bins[w][lane];
}

// ---------------- K3: per-(b,t) emission ---------------------------------------
// Prefix over chunks < ch read directly (independent coalesced loads, 4 accs);
// own chunk masked + ds_add. No separate scan kernel.
__global__ __launch_bounds__(256) void k_emit(const int* __restrict__ idx,
                                              const float* __restrict__ P,
                                              const float* __restrict__ hist,
                                              const float* __restrict__ Wv,
                                              float* __restrict__ out) {
  __shared__ float bins[4][64];
  const int tg = blockIdx.x;      // t = tg*4 + w
  const int b  = blockIdx.y;
  const int w = threadIdx.x >> 6;
  const int lane = threadIdx.x & 63;
  const int t = tg * 4 + w;
  const int c = idx[b * LSEQ + t];            // wave-uniform
  const int bc = b * 64 + c;
  const int ch = t >> 6;                      // CS == 64
  const int s0 = ch * 64;
  const int rel = t - s0;

  float p = P[(size_t)bc * LSEQ + s0 + lane];
  const int ii = idx[b * LSEQ + s0 + lane];
  p = (lane <= rel) ? p : 0.f;                // causal mask
  bins[w][lane] = 0.f;
  __syncthreads();
  atomicAdd(&bins[w][ii], p);
  __syncthreads();

  // prefix over earlier chunks: independent loads, 4 accumulators
  const float* __restrict__ h = hist + (size_t)bc * NC * 64 + lane;
  float t0 = 0.f, t1 = 0.f, t2 = 0.f, t3 = 0.f;
  int ch2 = 0;
  for (; ch2 + 4 <= ch; ch2 += 4) {
    t0 += h[(ch2 + 0) * 64];
    t1 += h[(ch2 + 1) * 64];
    t2 += h[(ch2 + 2) * 64];
    t3 += h[(ch2 + 3) * 64];
  }
  for (; ch2 < ch; ++ch2) t0 += h[ch2 * 64];
  float bin = bins[w][lane] + ((t0 + t1) + (t2 + t3));

  float z = bin;
#pragma unroll
  for (int d = 1; d < 64; d <<= 1) z += __shfl_xor(z, d);
  out[((size_t)(b * LSEQ + t)) * 64 + lane] = Wv[0] * bin / z;
}

extern "C" void kernel_launch(void* const* d_in, const int* in_sizes, int n_in,
                              void* d_out, int out_size, void* d_ws, size_t ws_size,
                              hipStream_t stream) {
  const int* idx     = (const int*)d_in[0];     // [16, 2048]
  const float* Wq    = (const float*)d_in[1];   // [64, 64]
  const float* Wv    = (const float*)d_in[2];   // [64, 64] (only [0,0] used)
  const float* v_emb = (const float*)d_in[3];   // [2048, 1]
  float* out = (float*)d_out;                   // [16, 2048, 64] fp32

  // workspace: S[2048] f32 | P[1024*2048] f32 | hist[1024*32*64] f32 |
  //            Ebf[2048] bf16 | Agr[16*256*64*8] bf16   (~20.5 MB)
  float* S = (float*)d_ws;
  float* P = S + LSEQ;
  float* hist = P + (size_t)NB * NV * LSEQ;
  unsigned short* Ebf = (unsigned short*)(hist + (size_t)NB * NV * NC * 64);
  unsigned short* Agr = Ebf + LSEQ;

  k_gather<<<NB * 16, 256, 0, stream>>>(idx, Wq, v_emb, Agr, Ebf, S);
  k_gemm<<<dim3(64, NB), 256, 0, stream>>>(Agr, Ebf, S, P);
  k_chist<<<dim3(NC, 16, NB), 256, 0, stream>>>(idx, P, hist);
  k_emit<<<dim3(LSEQ / 4, NB), 256, 0, stream>>>(idx, P, hist, Wv, out);
}